// Round 1
// baseline (321766.016 us; speedup 1.0000x reference)
//
#include <hip/hip_runtime.h>

// Persistent single-kernel implementation of the attention-LSTM decoder.
// Grid = 256 blocks x 512 threads (co-resident on 256 CUs), custom device-scope
// barrier between phases. All math fp32 (round-0 accuracy anchor).
//
// Dims (fixed by setup_inputs):
#define BSZ  32     // batch
#define NPIX 640    // P
#define EDIM 512    // E (encoder dim)
#define SLEN 256    // L (max caption len)
#define VOC  8000   // V
#define ADIM 512    // A
#define DDIM 512    // D
#define SDIM 256    // S
#define EMD  256    // ED
#define TT   255    // T = L-1

#define NBLK 256
#define NTHR 512

// ---- workspace layout (int indices into ws) ----
#define WSI_BAR  0          // barrier counter (memset to 0 pre-launch)
#define WSI_SORT 1          // [32] sort_ind
#define WSI_CL   33         // [32] sorted lengths
#define WSI_DEC  65         // [32] decode lengths
#define WSI_CAPS 97         // [32*256] sorted captions
// ---- float offsets ----
#define F_MEAN  8320        // [512] mean_enc
#define F_ATT1  8832        // [640*512]
#define F_ATT3B 336512      // [32*512]  att3 + bs + bd
#define F_H     352896      // [32*512]
#define F_C     369280      // [32*512]
#define F_U     385664      // [32*512]  att2+att3b
#define F_G     402048      // [32*512]  sigmoid gate
#define F_HH    418432      // [32*2048] h @ Whh
#define F_EMBT  483968      // [32*256]
#define F_WEXP  492160      // [32*640]  exp(e)
#define F_PDEN  512640      // [32*8]    partial denominators
#define F_PAWE  512896      // [8*32*512] partial awe numerators
#define F_HST   643968      // [255*32*512] h history
// total floats: 4,821,888  (~19.3 MB)

// ---- output layout (floats, concatenated in return order) ----
#define O_PRED 0
#define O_CAPS 65280000
#define O_DEC  65288192
#define O_ALPH 65288224
#define O_SORT 70510624

__device__ __forceinline__ float sigm(float x) { return 1.f / (1.f + expf(-x)); }

// Monotone-counter grid barrier. Requires all NBLK blocks resident (true:
// 256 blocks, <=40KB LDS, <=256 VGPR -> >=2 blocks/CU capacity).
__device__ __forceinline__ void gbar(unsigned int* cnt, unsigned int target) {
  __syncthreads();
  if (threadIdx.x == 0) {
    __threadfence();  // release all prior global writes (agent scope)
    __hip_atomic_fetch_add(cnt, 1u, __ATOMIC_RELEASE, __HIP_MEMORY_SCOPE_AGENT);
    while (__hip_atomic_load(cnt, __ATOMIC_ACQUIRE, __HIP_MEMORY_SCOPE_AGENT) < target)
      __builtin_amdgcn_s_sleep(1);
    __threadfence();  // acquire
  }
  __syncthreads();
}

__global__ __launch_bounds__(NTHR, 2) void decoder_persistent(
    const float* __restrict__ enc, const int* __restrict__ caps_in,
    const int* __restrict__ cl_in, const float* __restrict__ hs,
    const float* __restrict__ emb,
    const float* We, const float* be, const float* Wd, const float* bd,
    const float* Wsx, const float* bsx, const float* Wf, const float* bf,
    const float* Wih, const float* bih, const float* Whh, const float* bhh,
    const float* Wh0, const float* bh0, const float* Wc0, const float* bc0,
    const float* Wg, const float* bg, const float* Wo, const float* bo,
    float* __restrict__ out, int* __restrict__ wsI) {
  const int tid = threadIdx.x;
  const int blk = blockIdx.x;
  float* wsF = (float*)wsI;
  unsigned int* bar = (unsigned int*)&wsI[WSI_BAR];
  unsigned int barno = 0;
  __shared__ __align__(16) float sm[8352];

  // ================= P0: sort + mean_enc =================
  if (blk == 0 && tid == 0) {
    // stable descending selection sort (matches jnp.argsort(-cl))
    int cl[BSZ];
    bool used[BSZ];
    for (int i = 0; i < BSZ; i++) { cl[i] = cl_in[i]; used[i] = false; }
    for (int r = 0; r < BSZ; r++) {
      int best = -1, bv = -1;
      for (int i = 0; i < BSZ; i++)
        if (!used[i] && cl[i] > bv) { bv = cl[i]; best = i; }
      used[best] = true;
      wsI[WSI_SORT + r] = best;
      wsI[WSI_CL + r] = bv;
      wsI[WSI_DEC + r] = bv - 1;
      out[O_DEC + r] = (float)(bv - 1);
      out[O_SORT + r] = (float)best;
    }
  }
  if (blk == 1) {
    for (int d = tid; d < EDIM; d += NTHR) {
      float s = 0.f;
      for (int p = 0; p < NPIX; p++) s += enc[p * EDIM + d];
      wsF[F_MEAN + d] = s * (1.f / NPIX);
    }
  }
  gbar(bar, ++barno * NBLK);

  // ================= P1: att1, att3b, h0/c0, caps out =================
  if (blk < 64) {  // att1 = enc @ We + be   (640x512)
    for (int pp = 0; pp < 10; pp++) {
      int p = blk * 10 + pp;
      int a = tid;
      float s = be[a];
      for (int k = 0; k < EDIM; k++) s = fmaf(enc[p * EDIM + k], We[k * ADIM + a], s);
      wsF[F_ATT1 + p * ADIM + a] = s;
    }
  } else if (blk < 96) {  // att3b[b] = hs_sorted @ Ws + bs + bd
    int b = blk - 64;
    int a = tid;
    int src = wsI[WSI_SORT + b];
    float s = bsx[a] + bd[a];
    for (int k = 0; k < SDIM; k++) s = fmaf(hs[src * SDIM + k], Wsx[k * ADIM + a], s);
    wsF[F_ATT3B + b * ADIM + a] = s;
  } else if (blk == 96) {  // h0/c0 (identical across batch)
    int d = tid;
    float ha = bh0[d], ca = bc0[d];
    for (int e = 0; e < EDIM; e++) {
      float m = wsF[F_MEAN + e];
      ha = fmaf(m, Wh0[e * DDIM + d], ha);
      ca = fmaf(m, Wc0[e * DDIM + d], ca);
    }
    for (int b = 0; b < BSZ; b++) {
      wsF[F_H + b * DDIM + d] = ha;
      wsF[F_C + b * DDIM + d] = ca;
    }
  } else if (blk >= 97 && blk < 129) {  // sorted caps -> ws + out
    int b = blk - 97;
    if (tid < SLEN) {
      int src = wsI[WSI_SORT + b];
      int cv = caps_in[src * SLEN + tid];
      wsI[WSI_CAPS + b * SLEN + tid] = cv;
      out[O_CAPS + b * SLEN + tid] = (float)cv;
    }
  }
  gbar(bar, ++barno * NBLK);

  // ================= sequential decode loop =================
  for (int t = 0; t < TT; t++) {
    // ---- Phase A: u = h@Wd + att3b ; g = sigm(h@Wg+bg) ; hh = h@Whh ; emb gather ----
    if (blk < 96) {
      const int c = tid & 31;
      const int bq = tid >> 5;  // 0..15 -> rows bq and bq+16
      const int cc = blk * 32 + c;
      const float* Wsel;
      int wstride, wcol;
      if (cc < 512)      { Wsel = Wd;  wstride = 512;  wcol = cc; }
      else if (cc < 1024){ Wsel = Wg;  wstride = 512;  wcol = cc - 512; }
      else               { Wsel = Whh; wstride = 2048; wcol = cc - 1024; }
      float acc1 = 0.f, acc2 = 0.f;
      for (int kh = 0; kh < 2; kh++) {
        __syncthreads();
        for (int i = tid; i < 8192; i += NTHR)
          sm[i] = wsF[F_H + (i >> 8) * DDIM + kh * 256 + (i & 255)];
        __syncthreads();
        const float* wp = Wsel + (size_t)(kh * 256) * wstride + wcol;
        const float* h1p = &sm[bq * 256];
        const float* h2p = &sm[(bq + 16) * 256];
        for (int k = 0; k < 256; k += 4) {
          const float4 h1 = *(const float4*)&h1p[k];
          const float4 h2 = *(const float4*)&h2p[k];
          const float w0 = wp[(size_t)k * wstride];
          const float w1 = wp[(size_t)(k + 1) * wstride];
          const float w2 = wp[(size_t)(k + 2) * wstride];
          const float w3 = wp[(size_t)(k + 3) * wstride];
          acc1 = fmaf(h1.x, w0, acc1); acc2 = fmaf(h2.x, w0, acc2);
          acc1 = fmaf(h1.y, w1, acc1); acc2 = fmaf(h2.y, w1, acc2);
          acc1 = fmaf(h1.z, w2, acc1); acc2 = fmaf(h2.z, w2, acc2);
          acc1 = fmaf(h1.w, w3, acc1); acc2 = fmaf(h2.w, w3, acc2);
        }
      }
      if (cc < 512) {
        wsF[F_U + bq * ADIM + cc] = acc1 + wsF[F_ATT3B + bq * ADIM + cc];
        wsF[F_U + (bq + 16) * ADIM + cc] = acc2 + wsF[F_ATT3B + (bq + 16) * ADIM + cc];
      } else if (cc < 1024) {
        wsF[F_G + bq * EDIM + wcol] = sigm(acc1 + bg[wcol]);
        wsF[F_G + (bq + 16) * EDIM + wcol] = sigm(acc2 + bg[wcol]);
      } else {
        wsF[F_HH + bq * 2048 + wcol] = acc1;
        wsF[F_HH + (bq + 16) * 2048 + wcol] = acc2;
      }
    } else if (blk == 96) {  // embedding gather for step t
      for (int i = tid; i < BSZ * EMD; i += NTHR) {
        int b = i >> 8, j = i & 255;
        int tok = wsI[WSI_CAPS + b * SLEN + t];
        wsF[F_EMBT + i] = emb[tok * EMD + j];
      }
    }
    gbar(bar, ++barno * NBLK);

    // ---- Phase B: e, exp(e), partial denom, partial awe (per (b, p-tile)) ----
    {
      const int b = blk >> 3;
      const int pt = blk & 7;
      __syncthreads();
      sm[tid] = wsF[F_U + b * ADIM + tid];  // u_s
      sm[512 + tid] = Wf[tid];              // wf_s
      __syncthreads();
      const int wave = tid >> 6, lane = tid & 63;
      const float bf0 = bf[0];
      float dl = 0.f;
      for (int j = 0; j < 10; j++) {
        int pi = wave + j * 8;
        int p = pt * 80 + pi;
        const float* a1 = &wsF[F_ATT1 + (size_t)p * ADIM];
        float s = 0.f;
        for (int q = 0; q < 8; q++) {
          int a = lane + q * 64;
          float v = fmaxf(a1[a] + sm[a], 0.f);
          s = fmaf(v, sm[512 + a], s);
        }
        s += __shfl_xor(s, 1);  s += __shfl_xor(s, 2);  s += __shfl_xor(s, 4);
        s += __shfl_xor(s, 8);  s += __shfl_xor(s, 16); s += __shfl_xor(s, 32);
        float ex = expf(s + bf0);  // no max-subtraction: e is O(+-5), exact ratio
        if (lane == 0) {
          sm[1024 + pi] = ex;
          wsF[F_WEXP + b * NPIX + p] = ex;
          dl += ex;
        }
      }
      if (lane == 0) sm[1104 + wave] = dl;
      __syncthreads();
      if (tid == 0) {
        float pd = 0.f;
        for (int w = 0; w < 8; w++) pd += sm[1104 + w];
        wsF[F_PDEN + b * 8 + pt] = pd;
      }
      {  // partial awe numerator over this p-tile, all 512 enc dims
        int ec = tid;
        float acc = 0.f;
        const float* eb = &enc[(size_t)(pt * 80) * EDIM + ec];
        for (int i = 0; i < 80; i++) acc = fmaf(sm[1024 + i], eb[(size_t)i * EDIM], acc);
        wsF[F_PAWE + (size_t)(pt * BSZ + b) * EDIM + ec] = acc;
      }
    }
    gbar(bar, ++barno * NBLK);

    // ---- Phase D: gates (Wih) + LSTM pointwise + h/c update; alpha output ----
    if (blk < 32) {
      const int d0 = blk * 16;
      const int di = tid & 15;
      const int b = tid >> 4;  // 0..31
      __syncthreads();
      if (tid < 32) {
        float den = 0.f;
        for (int pt = 0; pt < 8; pt++) den += wsF[F_PDEN + tid * 8 + pt];
        sm[8192 + tid] = 1.f / den;
      }
      float acc0 = 0.f, acc1 = 0.f, acc2 = 0.f, acc3 = 0.f;
      const int j0 = d0 + di;
      for (int k = 0; k < EMD; k++) {  // embedding rows of Wih
        float ev = wsF[F_EMBT + b * EMD + k];
        const float* wr = &Wih[(size_t)k * 2048 + j0];
        acc0 = fmaf(ev, wr[0], acc0);
        acc1 = fmaf(ev, wr[512], acc1);
        acc2 = fmaf(ev, wr[1024], acc2);
        acc3 = fmaf(ev, wr[1536], acc3);
      }
      __syncthreads();  // rden ready
      for (int rh = 0; rh < 2; rh++) {  // gated-awe rows of Wih, in halves
        for (int i = tid; i < 8192; i += NTHR) {
          int bb = i >> 8, rr = rh * 256 + (i & 255);
          float aw = 0.f;
          for (int pt = 0; pt < 8; pt++) aw += wsF[F_PAWE + (size_t)(pt * BSZ + bb) * EDIM + rr];
          sm[i] = wsF[F_G + bb * EDIM + rr] * aw * sm[8192 + bb];
        }
        __syncthreads();
        for (int k = 0; k < 256; k++) {
          float xv = sm[b * 256 + k];
          const float* wr = &Wih[(size_t)(256 + rh * 256 + k) * 2048 + j0];
          acc0 = fmaf(xv, wr[0], acc0);
          acc1 = fmaf(xv, wr[512], acc1);
          acc2 = fmaf(xv, wr[1024], acc2);
          acc3 = fmaf(xv, wr[1536], acc3);
        }
        __syncthreads();
      }
      const int d = j0;
      float iv = acc0 + bih[d] + bhh[d] + wsF[F_HH + b * 2048 + d];
      float fv = acc1 + bih[512 + d] + bhh[512 + d] + wsF[F_HH + b * 2048 + 512 + d];
      float gv = acc2 + bih[1024 + d] + bhh[1024 + d] + wsF[F_HH + b * 2048 + 1024 + d];
      float ov = acc3 + bih[1536 + d] + bhh[1536 + d] + wsF[F_HH + b * 2048 + 1536 + d];
      float co = wsF[F_C + b * DDIM + d], ho = wsF[F_H + b * DDIM + d];
      float cn = sigm(fv) * co + sigm(iv) * tanhf(gv);
      float hn = sigm(ov) * tanhf(cn);
      bool act = t < wsI[WSI_DEC + b];
      float hw = act ? hn : ho;
      float cw = act ? cn : co;
      wsF[F_H + b * DDIM + d] = hw;
      wsF[F_C + b * DDIM + d] = cw;
      wsF[F_HST + (size_t)(t * BSZ + b) * DDIM + d] = hw;
    } else if (blk < 64) {  // alphas output row (b, t) -- single writer
      int b = blk - 32;
      bool act = t < wsI[WSI_DEC + b];
      float rd = 0.f;
      if (act) {
        float den = 0.f;
        for (int pt = 0; pt < 8; pt++) den += wsF[F_PDEN + b * 8 + pt];
        rd = 1.f / den;
      }
      for (int p = tid; p < NPIX; p += NTHR)
        out[O_ALPH + (size_t)(b * TT + t) * NPIX + p] =
            act ? wsF[F_WEXP + b * NPIX + p] * rd : 0.f;
    }
    gbar(bar, ++barno * NBLK);
  }

  // ================= Epilogue: preds = hstore @ Wo + bo (masked) =================
  // tiles: (col-tile 256) x (timestep t, rows = 32 batch). idx ordered so a
  // block sweeps t's within one col-tile (Wo tile stays L2-hot).
  const int cq = tid & 63;   // 64 col groups x 4 cols
  const int rq = tid >> 6;   // 0..7 -> rows rq*4..+3
  for (int idx = blk; idx < 32 * TT; idx += NBLK) {
    int ct = idx / TT;
    int tt = idx % TT;
    int col4 = ct * 256 + cq * 4;
    float4 a0 = {0, 0, 0, 0}, a1 = {0, 0, 0, 0}, a2 = {0, 0, 0, 0}, a3 = {0, 0, 0, 0};
    for (int kh = 0; kh < 2; kh++) {
      __syncthreads();
      for (int i = tid; i < 8192; i += NTHR)
        sm[i] = wsF[F_HST + (size_t)(tt * BSZ + (i >> 8)) * DDIM + kh * 256 + (i & 255)];
      __syncthreads();
      if (col4 < VOC) {
        const float* wop = &Wo[(size_t)(kh * 256) * VOC + col4];
        for (int k = 0; k < 256; k += 4) {
          const float4 w0 = *(const float4*)&wop[(size_t)(k + 0) * VOC];
          const float4 w1 = *(const float4*)&wop[(size_t)(k + 1) * VOC];
          const float4 w2 = *(const float4*)&wop[(size_t)(k + 2) * VOC];
          const float4 w3 = *(const float4*)&wop[(size_t)(k + 3) * VOC];
          const float4 h0 = *(const float4*)&sm[(rq * 4 + 0) * 256 + k];
          const float4 h1 = *(const float4*)&sm[(rq * 4 + 1) * 256 + k];
          const float4 h2 = *(const float4*)&sm[(rq * 4 + 2) * 256 + k];
          const float4 h3 = *(const float4*)&sm[(rq * 4 + 3) * 256 + k];
#define ROWFMA(ACC, HV)                                                      \
  ACC.x = fmaf(HV.x, w0.x, ACC.x); ACC.y = fmaf(HV.x, w0.y, ACC.y);          \
  ACC.z = fmaf(HV.x, w0.z, ACC.z); ACC.w = fmaf(HV.x, w0.w, ACC.w);          \
  ACC.x = fmaf(HV.y, w1.x, ACC.x); ACC.y = fmaf(HV.y, w1.y, ACC.y);          \
  ACC.z = fmaf(HV.y, w1.z, ACC.z); ACC.w = fmaf(HV.y, w1.w, ACC.w);          \
  ACC.x = fmaf(HV.z, w2.x, ACC.x); ACC.y = fmaf(HV.z, w2.y, ACC.y);          \
  ACC.z = fmaf(HV.z, w2.z, ACC.z); ACC.w = fmaf(HV.z, w2.w, ACC.w);          \
  ACC.x = fmaf(HV.w, w3.x, ACC.x); ACC.y = fmaf(HV.w, w3.y, ACC.y);          \
  ACC.z = fmaf(HV.w, w3.z, ACC.z); ACC.w = fmaf(HV.w, w3.w, ACC.w);
          ROWFMA(a0, h0) ROWFMA(a1, h1) ROWFMA(a2, h2) ROWFMA(a3, h3)
#undef ROWFMA
        }
      }
    }
    if (col4 < VOC) {
      const float4 bo4 = *(const float4*)&bo[col4];
      float4 accs[4] = {a0, a1, a2, a3};
      for (int r = 0; r < 4; r++) {
        int b = rq * 4 + r;
        bool act = tt < wsI[WSI_DEC + b];
        float4 o;
        o.x = act ? accs[r].x + bo4.x : 0.f;
        o.y = act ? accs[r].y + bo4.y : 0.f;
        o.z = act ? accs[r].z + bo4.z : 0.f;
        o.w = act ? accs[r].w + bo4.w : 0.f;
        *(float4*)&out[O_PRED + (size_t)(b * TT + tt) * VOC + col4] = o;
      }
    }
  }
}

extern "C" void kernel_launch(void* const* d_in, const int* in_sizes, int n_in,
                              void* d_out, int out_size, void* d_ws, size_t ws_size,
                              hipStream_t stream) {
  (void)in_sizes; (void)n_in; (void)out_size; (void)ws_size;
  const float* enc  = (const float*)d_in[0];
  const int* caps   = (const int*)d_in[1];
  const int* cl     = (const int*)d_in[2];
  const float* hs   = (const float*)d_in[3];
  // d_in[4] = batch_size (compile-time 32)
  const float* emb  = (const float*)d_in[5];
  const float* We   = (const float*)d_in[6];  const float* be  = (const float*)d_in[7];
  const float* Wd   = (const float*)d_in[8];  const float* bd  = (const float*)d_in[9];
  const float* Wsx  = (const float*)d_in[10]; const float* bsx = (const float*)d_in[11];
  const float* Wf   = (const float*)d_in[12]; const float* bf  = (const float*)d_in[13];
  const float* Wih  = (const float*)d_in[14]; const float* bih = (const float*)d_in[15];
  const float* Whh  = (const float*)d_in[16]; const float* bhh = (const float*)d_in[17];
  const float* Wh0  = (const float*)d_in[18]; const float* bh0 = (const float*)d_in[19];
  const float* Wc0  = (const float*)d_in[20]; const float* bc0 = (const float*)d_in[21];
  const float* Wg   = (const float*)d_in[22]; const float* bg  = (const float*)d_in[23];
  const float* Wo   = (const float*)d_in[24]; const float* bo  = (const float*)d_in[25];

  hipMemsetAsync(d_ws, 0, 4, stream);  // zero the barrier counter
  decoder_persistent<<<dim3(NBLK), dim3(NTHR), 0, stream>>>(
      enc, caps, cl, hs, emb, We, be, Wd, bd, Wsx, bsx, Wf, bf, Wih, bih, Whh,
      bhh, Wh0, bh0, Wc0, bc0, Wg, bg, Wo, bo, (float*)d_out, (int*)d_ws);
}

// Round 2
// 135388.147 us; speedup vs baseline: 2.3766x; 2.3766x over previous
//
#include <hip/hip_runtime.h>

// Persistent single-kernel attention-LSTM decoder, round 2.
// Key change vs round 1: NO agent-scope fences anywhere (they lower to
// buffer_wbl2/buffer_inv on gfx950 and flushed L2 every barrier -> 322ms).
// All per-step cross-block state moves via relaxed AGENT-scope atomics
// (sc1: bypass local L2, coherent at L3). Weights/att1/enc use plain loads
// and stay L2-resident across all 255 steps. Barrier = relaxed atomic
// counter; __syncthreads drains each wave's vmcnt so sc1 stores are at the
// coherence point before the counter increment.

#define BSZ  32
#define NPIX 640
#define EDIM 512
#define SLEN 256
#define VOC  8000
#define ADIM 512
#define DDIM 512
#define SDIM 256
#define EMD  256
#define TT   255

#define NBLK 256
#define NTHR 512

// ---- int ws indices ----
#define WSI_BAR  0
#define WSI_SORT 1
#define WSI_CL   33
#define WSI_DEC  65
#define WSI_CAPS 97          // [32*256]
// ---- float ws offsets ----
#define F_MEAN  8320         // [512]
#define F_ATT1  8832         // [640*512]
#define F_ATT3B 336512       // [32*512] att3 + bs + bd
#define F_H0    352896       // [32*512] h ping
#define F_H1    369280       // [32*512] h pong
#define F_C     385664       // [32*512] (block-private per d-slice)
#define F_U     402048       // [32*512]
#define F_G     418432       // [32*512]
#define F_EMBT  434816       // [32*256]
#define F_WEXP  443008       // [32*640]
#define F_DEN   463488       // [32]  atomic softmax denominator
#define F_AWE   463520       // [32*512] atomic awe numerator
#define F_HST   479904       // [255*32*512] h history
// total 4,657,824 floats ~= 18.6 MB (< round-1 footprint, fits ws)

// ---- output layout ----
#define O_PRED 0
#define O_CAPS 65280000
#define O_DEC  65288192
#define O_ALPH 65288224
#define O_SORT 70510624

__device__ __forceinline__ float sigm(float x) { return 1.f / (1.f + expf(-x)); }

// sc1 (device-coherent, L2-bypass) accessors -- no cache maintenance emitted.
__device__ __forceinline__ void stg(float* p, float v) {
  __hip_atomic_store(p, v, __ATOMIC_RELAXED, __HIP_MEMORY_SCOPE_AGENT);
}
__device__ __forceinline__ float ldgc(const float* p) {
  return __hip_atomic_load(p, __ATOMIC_RELAXED, __HIP_MEMORY_SCOPE_AGENT);
}
__device__ __forceinline__ void stgi(int* p, int v) {
  __hip_atomic_store(p, v, __ATOMIC_RELAXED, __HIP_MEMORY_SCOPE_AGENT);
}
__device__ __forceinline__ int ldgi(const int* p) {
  return __hip_atomic_load(p, __ATOMIC_RELAXED, __HIP_MEMORY_SCOPE_AGENT);
}
__device__ __forceinline__ void atadd(float* p, float v) {
  __hip_atomic_fetch_add(p, v, __ATOMIC_RELAXED, __HIP_MEMORY_SCOPE_AGENT);
}

// Flush-free grid barrier. __syncthreads drains each wave's vmcnt (sc1
// stores reach the coherence point); relaxed atomic counter; no fences.
__device__ __forceinline__ void gbar(unsigned int* cnt, unsigned int target) {
  __syncthreads();
  if (threadIdx.x == 0) {
    __hip_atomic_fetch_add(cnt, 1u, __ATOMIC_RELAXED, __HIP_MEMORY_SCOPE_AGENT);
    while (__hip_atomic_load(cnt, __ATOMIC_RELAXED, __HIP_MEMORY_SCOPE_AGENT) < target)
      __builtin_amdgcn_s_sleep(4);
  }
  __syncthreads();
}

__global__ __launch_bounds__(NTHR, 2) void decoder_persistent(
    const float* __restrict__ enc, const int* __restrict__ caps_in,
    const int* __restrict__ cl_in, const float* __restrict__ hs,
    const float* __restrict__ emb,
    const float* We, const float* be, const float* Wd, const float* bd,
    const float* Wsx, const float* bsx, const float* Wf, const float* bf,
    const float* Wih, const float* bih, const float* Whh, const float* bhh,
    const float* Wh0, const float* bh0, const float* Wc0, const float* bc0,
    const float* Wg, const float* bg, const float* Wo, const float* bo,
    float* __restrict__ out, int* __restrict__ wsI) {
  const int tid = threadIdx.x;
  const int blk = blockIdx.x;
  float* wsF = (float*)wsI;
  unsigned int* bar = (unsigned int*)&wsI[WSI_BAR];
  unsigned int barno = 0;
  __shared__ __align__(16) float sm[8192 + 512];
  float* smg = &sm[8192];

  // ================= P0: sort + mean_enc =================
  if (blk == 0 && tid == 0) {
    int cl[BSZ]; bool used[BSZ];
    for (int i = 0; i < BSZ; i++) { cl[i] = cl_in[i]; used[i] = false; }
    for (int r = 0; r < BSZ; r++) {
      int best = -1, bv = -1;
      for (int i = 0; i < BSZ; i++)
        if (!used[i] && cl[i] > bv) { bv = cl[i]; best = i; }
      used[best] = true;
      stgi(&wsI[WSI_SORT + r], best);
      stgi(&wsI[WSI_CL + r], bv);
      stgi(&wsI[WSI_DEC + r], bv - 1);
      out[O_DEC + r] = (float)(bv - 1);
      out[O_SORT + r] = (float)best;
    }
  }
  if (blk == 1) {
    for (int d = tid; d < EDIM; d += NTHR) {
      float s = 0.f;
      for (int p = 0; p < NPIX; p++) s += enc[p * EDIM + d];
      stg(&wsF[F_MEAN + d], s * (1.f / NPIX));
    }
  }
  gbar(bar, ++barno * NBLK);

  // ================= P1: att1, att3b, h0/c0, caps =================
  if (blk < 64) {  // att1 = enc @ We + be
    for (int pp = 0; pp < 10; pp++) {
      int p = blk * 10 + pp;
      int a = tid;
      float s = be[a];
      for (int k = 0; k < EDIM; k++) s = fmaf(enc[p * EDIM + k], We[k * ADIM + a], s);
      stg(&wsF[F_ATT1 + (size_t)p * ADIM + a], s);
    }
  } else if (blk < 96) {  // att3b = hs_sorted @ Ws + bs + bd
    int b = blk - 64;
    int a = tid;
    int src = ldgi(&wsI[WSI_SORT + b]);
    float s = bsx[a] + bd[a];
    for (int k = 0; k < SDIM; k++) s = fmaf(hs[src * SDIM + k], Wsx[k * ADIM + a], s);
    stg(&wsF[F_ATT3B + b * ADIM + a], s);
  } else if (blk == 96) {  // h0/c0 (same across batch)
    int d = tid;
    float ha = bh0[d], ca = bc0[d];
    for (int e = 0; e < EDIM; e++) {
      float m = ldgc(&wsF[F_MEAN + e]);
      ha = fmaf(m, Wh0[e * DDIM + d], ha);
      ca = fmaf(m, Wc0[e * DDIM + d], ca);
    }
    for (int b = 0; b < BSZ; b++) {
      stg(&wsF[F_H0 + b * DDIM + d], ha);
      stg(&wsF[F_C + b * DDIM + d], ca);
    }
  } else if (blk >= 97 && blk < 129) {  // sorted caps
    int b = blk - 97;
    if (tid < SLEN) {
      int src = ldgi(&wsI[WSI_SORT + b]);
      int cv = caps_in[src * SLEN + tid];
      stgi(&wsI[WSI_CAPS + b * SLEN + tid], cv);
      out[O_CAPS + b * SLEN + tid] = (float)cv;
    }
  }
  gbar(bar, ++barno * NBLK);

  // ================= decode loop: 3 phases/step =================
  for (int t = 0; t < TT; t++) {
    const int FH_rd = (t & 1) ? F_H1 : F_H0;
    const int FH_wr = (t & 1) ? F_H0 : F_H1;

    // ---- Phase A: u = h@Wd + att3b (blk 0-31); g = sigm(h@Wg+bg) (32-63);
    //      embt gather (64); zero AWE (65-66); zero DEN (67) ----
    if (blk < 64) {
      const bool isWd = blk < 32;
      const int c = tid & 15, b = tid >> 4;
      const int col = (isWd ? blk : blk - 32) * 16 + c;
      const float* W = isWd ? Wd : Wg;
      float acc = 0.f;
      for (int kh = 0; kh < 2; kh++) {
        __syncthreads();
        {
          int base = b * 256 + (c << 4);
          int gk = kh * 256 + (c << 4);
          for (int q = 0; q < 16; q++)
            sm[base + q] = ldgc(&wsF[FH_rd + b * DDIM + gk + q]);
        }
        __syncthreads();
        const float* wp = W + (size_t)(kh * 256) * ADIM + col;
        const float* xr = &sm[b * 256];
        for (int k = 0; k < 256; k++)
          acc = fmaf(xr[k], wp[(size_t)k * ADIM], acc);  // xr: LDS broadcast; wp: L2-hot
      }
      if (isWd) stg(&wsF[F_U + b * ADIM + col], acc + wsF[F_ATT3B + b * ADIM + col]);
      else      stg(&wsF[F_G + b * EDIM + col], sigm(acc + bg[col]));
    } else if (blk == 64) {  // embedding gather
      for (int i = tid; i < BSZ * EMD; i += NTHR) {
        int b = i >> 8, j = i & 255;
        int tok = wsI[WSI_CAPS + b * SLEN + t];  // write-once, plain OK
        stg(&wsF[F_EMBT + i], emb[tok * EMD + j]);
      }
    } else if (blk == 65 || blk == 66) {  // zero awe accumulator
      int base = (blk - 65) * 8192;
      for (int i = tid; i < 8192; i += NTHR) stg(&wsF[F_AWE + base + i], 0.f);
    } else if (blk == 67) {
      if (tid < BSZ) stg(&wsF[F_DEN + tid], 0.f);
    }
    gbar(bar, ++barno * NBLK);

    // ---- Phase B: e, exp, atomic denom + atomic awe (block = (b, p-tile)) ----
    {
      const int b = blk >> 3;
      const int pt = blk & 7;
      __syncthreads();
      sm[tid] = ldgc(&wsF[F_U + b * ADIM + tid]);  // u
      sm[512 + tid] = Wf[tid];                      // plain, L2-hot
      __syncthreads();
      const int wave = tid >> 6, lane = tid & 63;
      const float bf0 = bf[0];
      float dl = 0.f;
      for (int j = 0; j < 10; j++) {
        int pi = wave + j * 8;
        int p = pt * 80 + pi;
        const float* a1 = &wsF[F_ATT1 + (size_t)p * ADIM];  // plain, L2-hot
        float s = 0.f;
        for (int q = 0; q < 8; q++) {
          int a = lane + q * 64;
          float v = fmaxf(a1[a] + sm[a], 0.f);
          s = fmaf(v, sm[512 + a], s);
        }
        s += __shfl_xor(s, 1);  s += __shfl_xor(s, 2);  s += __shfl_xor(s, 4);
        s += __shfl_xor(s, 8);  s += __shfl_xor(s, 16); s += __shfl_xor(s, 32);
        float ex = expf(s + bf0);  // e is O(+-5): no max-subtraction needed
        if (lane == 0) {
          sm[1024 + pi] = ex;
          stg(&wsF[F_WEXP + b * NPIX + p], ex);
          dl += ex;
        }
      }
      if (lane == 0) atadd(&wsF[F_DEN + b], dl);
      __syncthreads();
      {  // awe partial over this p-tile: atomic accumulate
        int ec = tid;
        float acc = 0.f;
        const float* eb = &enc[(size_t)(pt * 80) * EDIM + ec];
        for (int i = 0; i < 80; i++) acc = fmaf(sm[1024 + i], eb[(size_t)i * EDIM], acc);
        atadd(&wsF[F_AWE + b * EDIM + ec], acc);
      }
    }
    gbar(bar, ++barno * NBLK);

    // ---- Phase D: gates = [emb, g*awe/den, h] @ [Wih;Whh] (blk 0-127, 4 d-cols
    //      each, x LDS-broadcast) + pointwise; alphas (blk 128-159) ----
    if (blk < 128) {
      const int j = tid & 15, b = tid >> 4;
      const int jj = j & 3, gate = j >> 2;
      const int col = gate * 512 + blk * 4 + jj;
      const float rden = 1.f / ldgc(&wsF[F_DEN + b]);
      float acc = bih[col] + bhh[col];
      for (int s = 0; s < 5; s++) {
        __syncthreads();
        {
          int chunk = (tid & 15) << 4;
          int base = b * 256 + chunk;
          if (s == 0) {
            for (int q = 0; q < 16; q++)
              sm[base + q] = ldgc(&wsF[F_EMBT + b * EMD + chunk + q]);
          } else if (s < 3) {
            int rr = (s - 1) * 256 + chunk;
            for (int q = 0; q < 16; q++)
              sm[base + q] = ldgc(&wsF[F_G + b * EDIM + rr + q]) *
                             ldgc(&wsF[F_AWE + b * EDIM + rr + q]) * rden;
          } else {
            int rr = (s - 3) * 256 + chunk;
            for (int q = 0; q < 16; q++)
              sm[base + q] = ldgc(&wsF[FH_rd + b * DDIM + rr + q]);
          }
        }
        __syncthreads();
        const float* wp = (s < 3) ? Wih + (size_t)(s * 256) * 2048 + col
                                  : Whh + (size_t)((s - 3) * 256) * 2048 + col;
        const float* xr = &sm[b * 256];
        for (int k = 0; k < 256; k++)
          acc = fmaf(xr[k], wp[(size_t)k * 2048], acc);  // xr broadcast; wp L2-hot
      }
      __syncthreads();
      smg[b * 16 + j] = acc;
      __syncthreads();
      if (tid < 128) {
        int bb = tid >> 2, dd = tid & 3;
        int d = blk * 4 + dd;
        float iv = smg[bb * 16 + dd + 0];
        float fv = smg[bb * 16 + dd + 4];
        float gv = smg[bb * 16 + dd + 8];
        float ov = smg[bb * 16 + dd + 12];
        float co = wsF[F_C + bb * DDIM + d];  // block-private slice
        float ho = ldgc(&wsF[FH_rd + bb * DDIM + d]);
        float cn = sigm(fv) * co + sigm(iv) * tanhf(gv);
        float hn = sigm(ov) * tanhf(cn);
        bool act = t < wsI[WSI_DEC + bb];
        float hw = act ? hn : ho;
        float cw = act ? cn : co;
        wsF[F_C + bb * DDIM + d] = cw;
        stg(&wsF[FH_wr + bb * DDIM + d], hw);
        stg(&wsF[F_HST + ((size_t)t * BSZ + bb) * DDIM + d], hw);
      }
    } else if (blk < 160) {  // alphas row (b, t)
      int b = blk - 128;
      bool act = t < wsI[WSI_DEC + b];
      float rd = act ? 1.f / ldgc(&wsF[F_DEN + b]) : 0.f;
      for (int p = tid; p < NPIX; p += NTHR)
        out[O_ALPH + (size_t)(b * TT + t) * NPIX + p] =
            act ? ldgc(&wsF[F_WEXP + b * NPIX + p]) * rd : 0.f;
    }
    gbar(bar, ++barno * NBLK);
  }

  // ================= Epilogue: preds = hstore @ Wo + bo =================
  // F_HST was only ever touched with sc1 ops -> local L2s hold no stale
  // copies; plain (vectorized) loads are safe and fast here.
  const int cq = tid & 63;
  const int rq = tid >> 6;
  for (int idx = blk; idx < 32 * TT; idx += NBLK) {
    int ct = idx / TT;
    int tt = idx % TT;
    int col4 = ct * 256 + cq * 4;
    float4 a0 = {0,0,0,0}, a1 = {0,0,0,0}, a2 = {0,0,0,0}, a3 = {0,0,0,0};
    for (int kh = 0; kh < 2; kh++) {
      __syncthreads();
      for (int i = tid; i < 2048; i += NTHR) {
        int bb = i >> 6, kk = (i & 63) << 2;
        *(float4*)&sm[bb * 256 + kk] =
            *(const float4*)&wsF[F_HST + ((size_t)tt * BSZ + bb) * DDIM + kh * 256 + kk];
      }
      __syncthreads();
      if (col4 < VOC) {
        const float* wop = &Wo[(size_t)(kh * 256) * VOC + col4];
        for (int k = 0; k < 256; k += 4) {
          const float4 w0 = *(const float4*)&wop[(size_t)(k + 0) * VOC];
          const float4 w1 = *(const float4*)&wop[(size_t)(k + 1) * VOC];
          const float4 w2 = *(const float4*)&wop[(size_t)(k + 2) * VOC];
          const float4 w3 = *(const float4*)&wop[(size_t)(k + 3) * VOC];
          const float4 h0 = *(const float4*)&sm[(rq * 4 + 0) * 256 + k];
          const float4 h1 = *(const float4*)&sm[(rq * 4 + 1) * 256 + k];
          const float4 h2 = *(const float4*)&sm[(rq * 4 + 2) * 256 + k];
          const float4 h3 = *(const float4*)&sm[(rq * 4 + 3) * 256 + k];
#define ROWFMA(ACC, HV)                                                      \
  ACC.x = fmaf(HV.x, w0.x, ACC.x); ACC.y = fmaf(HV.x, w0.y, ACC.y);          \
  ACC.z = fmaf(HV.x, w0.z, ACC.z); ACC.w = fmaf(HV.x, w0.w, ACC.w);          \
  ACC.x = fmaf(HV.y, w1.x, ACC.x); ACC.y = fmaf(HV.y, w1.y, ACC.y);          \
  ACC.z = fmaf(HV.y, w1.z, ACC.z); ACC.w = fmaf(HV.y, w1.w, ACC.w);          \
  ACC.x = fmaf(HV.z, w2.x, ACC.x); ACC.y = fmaf(HV.z, w2.y, ACC.y);          \
  ACC.z = fmaf(HV.z, w2.z, ACC.z); ACC.w = fmaf(HV.z, w2.w, ACC.w);          \
  ACC.x = fmaf(HV.w, w3.x, ACC.x); ACC.y = fmaf(HV.w, w3.y, ACC.y);          \
  ACC.z = fmaf(HV.w, w3.z, ACC.z); ACC.w = fmaf(HV.w, w3.w, ACC.w);
          ROWFMA(a0, h0) ROWFMA(a1, h1) ROWFMA(a2, h2) ROWFMA(a3, h3)
#undef ROWFMA
        }
      }
    }
    if (col4 < VOC) {
      const float4 bo4 = *(const float4*)&bo[col4];
      float4 accs[4] = {a0, a1, a2, a3};
      for (int r = 0; r < 4; r++) {
        int b = rq * 4 + r;
        bool act = tt < wsI[WSI_DEC + b];
        float4 o;
        o.x = act ? accs[r].x + bo4.x : 0.f;
        o.y = act ? accs[r].y + bo4.y : 0.f;
        o.z = act ? accs[r].z + bo4.z : 0.f;
        o.w = act ? accs[r].w + bo4.w : 0.f;
        *(float4*)&out[O_PRED + (size_t)(b * TT + tt) * VOC + col4] = o;
      }
    }
  }
}

extern "C" void kernel_launch(void* const* d_in, const int* in_sizes, int n_in,
                              void* d_out, int out_size, void* d_ws, size_t ws_size,
                              hipStream_t stream) {
  (void)in_sizes; (void)n_in; (void)out_size; (void)ws_size;
  const float* enc  = (const float*)d_in[0];
  const int* caps   = (const int*)d_in[1];
  const int* cl     = (const int*)d_in[2];
  const float* hs   = (const float*)d_in[3];
  const float* emb  = (const float*)d_in[5];
  const float* We   = (const float*)d_in[6];  const float* be  = (const float*)d_in[7];
  const float* Wd   = (const float*)d_in[8];  const float* bd  = (const float*)d_in[9];
  const float* Wsx  = (const float*)d_in[10]; const float* bsx = (const float*)d_in[11];
  const float* Wf   = (const float*)d_in[12]; const float* bf  = (const float*)d_in[13];
  const float* Wih  = (const float*)d_in[14]; const float* bih = (const float*)d_in[15];
  const float* Whh  = (const float*)d_in[16]; const float* bhh = (const float*)d_in[17];
  const float* Wh0  = (const float*)d_in[18]; const float* bh0 = (const float*)d_in[19];
  const float* Wc0  = (const float*)d_in[20]; const float* bc0 = (const float*)d_in[21];
  const float* Wg   = (const float*)d_in[22]; const float* bg  = (const float*)d_in[23];
  const float* Wo   = (const float*)d_in[24]; const float* bo  = (const float*)d_in[25];

  hipMemsetAsync(d_ws, 0, 4, stream);  // zero the barrier counter
  decoder_persistent<<<dim3(NBLK), dim3(NTHR), 0, stream>>>(
      enc, caps, cl, hs, emb, We, be, Wd, bd, Wsx, bsx, Wf, bf, Wih, bih, Whh,
      bhh, Wh0, bh0, Wc0, bc0, Wg, bg, Wo, bo, (float*)d_out, (int*)d_ws);
}

// Round 3
// 43668.552 us; speedup vs baseline: 7.3684x; 3.1004x over previous
//
#include <hip/hip_runtime.h>

// Persistent single-kernel attention-LSTM decoder, round 3.
// Round-2 post-mortem: 97% latency stall from (a) column-strided scalar
// weight loads, (b) serialized scalar sc1 loads, (c) 16B-per-64B-sector Wih
// access thrashing per-XCD L2, (d) epilogue re-fetching Wo every iteration.
// This round: coalesced float4 weight streaming with L2-resident per-XCD
// slices, batched inline-asm sc1 (dwordx4, sc0 sc1) staging, fixed epilogue
// tile order, bf16-packed h history.

#define BSZ  32
#define NPIX 640
#define EDIM 512
#define SLEN 256
#define VOC  8000
#define ADIM 512
#define DDIM 512
#define SDIM 256
#define EMD  256
#define TT   255

#define NBLK 256
#define NTHR 512

typedef float f32x4 __attribute__((ext_vector_type(4)));
typedef float f32x2 __attribute__((ext_vector_type(2)));
typedef unsigned int uint32;

// ---- int ws indices ----
#define WSI_BAR  0
#define WSI_SORT 1
#define WSI_CL   33
#define WSI_DEC  65
#define WSI_CAPS 97          // [32*256]
// ---- float ws offsets (all %4==0) ----
#define F_MEAN  8320         // [512]
#define F_ATT1  8832         // [640*512]
#define F_ATT3B 336512       // [32*512] att3 + bs + bd
#define F_H0    352896       // [32*512]
#define F_H1    369280       // [32*512]
#define F_C     385664       // [32*512] block-private (plain)
#define F_U     402048       // [32*512]
#define F_G     418432       // [32*512]
#define F_HH    434816       // [32*2048]
#define F_EMBT  500352       // [32*256]
#define F_WEXP  508544       // [32*640]
#define F_DEN   529024       // [32]
#define F_AWE   529056       // [32*512]
#define F_HST   545440       // uint32[255*32*256] packed bf16 pairs

// ---- output layout ----
#define O_PRED 0
#define O_CAPS 65280000
#define O_DEC  65288192
#define O_ALPH 65288224
#define O_SORT 70510624

__device__ __forceinline__ float sigm(float x) { return 1.f / (1.f + expf(-x)); }

// ---- sc1 (device-coherent, L2-bypass) primitives ----
__device__ __forceinline__ void stg(float* p, float v) {
  __hip_atomic_store(p, v, __ATOMIC_RELAXED, __HIP_MEMORY_SCOPE_AGENT);
}
__device__ __forceinline__ void stgu(uint32* p, uint32 v) {
  __hip_atomic_store(p, v, __ATOMIC_RELAXED, __HIP_MEMORY_SCOPE_AGENT);
}
__device__ __forceinline__ float ldgc(const float* p) {
  return __hip_atomic_load(p, __ATOMIC_RELAXED, __HIP_MEMORY_SCOPE_AGENT);
}
__device__ __forceinline__ void stgi(int* p, int v) {
  __hip_atomic_store(p, v, __ATOMIC_RELAXED, __HIP_MEMORY_SCOPE_AGENT);
}
__device__ __forceinline__ void atadd(float* p, float v) {
  __hip_atomic_fetch_add(p, v, __ATOMIC_RELAXED, __HIP_MEMORY_SCOPE_AGENT);
}
// vectorized sc1: issue loads (no wait), then one VMWAIT before use.
#define LD4C_ISSUE(r, p) \
  asm volatile("global_load_dwordx4 %0, %1, off sc0 sc1" : "=v"(r) : "v"(p))
#define LD1C_ISSUE(r, p) \
  asm volatile("global_load_dword %0, %1, off sc0 sc1" : "=v"(r) : "v"(p))
#define VMWAIT() asm volatile("s_waitcnt vmcnt(0)" ::: "memory")
__device__ __forceinline__ void stg4(float* p, f32x4 v) {
  asm volatile("global_store_dwordx4 %0, %1, off sc0 sc1" :: "v"(p), "v"(v) : "memory");
}
__device__ __forceinline__ void stg2(float* p, f32x2 v) {
  asm volatile("global_store_dwordx2 %0, %1, off sc0 sc1" :: "v"(p), "v"(v) : "memory");
}
__device__ __forceinline__ f32x4 ld4c(const float* p) {
  f32x4 r;
  asm volatile("global_load_dwordx4 %0, %1, off sc0 sc1\n\ts_waitcnt vmcnt(0)"
               : "=v"(r) : "v"(p) : "memory");
  return r;
}
__device__ __forceinline__ uint32 packbf2(float x, float y) {
  uint32 ux = __float_as_uint(x); ux += 0x7FFFu + ((ux >> 16) & 1u);
  uint32 uy = __float_as_uint(y); uy += 0x7FFFu + ((uy >> 16) & 1u);
  return (ux >> 16) | (uy & 0xFFFF0000u);
}

// Flush-free grid barrier (no agent fences -> no L2 writeback/invalidate).
// VMWAIT drains this thread's sc1 stores to the coherence point first.
__device__ __forceinline__ void gbar(unsigned int* cnt, unsigned int target) {
  VMWAIT();
  __syncthreads();
  if (threadIdx.x == 0) {
    __hip_atomic_fetch_add(cnt, 1u, __ATOMIC_RELAXED, __HIP_MEMORY_SCOPE_AGENT);
    while (__hip_atomic_load(cnt, __ATOMIC_RELAXED, __HIP_MEMORY_SCOPE_AGENT) < target)
      __builtin_amdgcn_s_sleep(2);
  }
  __syncthreads();
}

__global__ __launch_bounds__(NTHR, 2) void decoder_persistent(
    const float* __restrict__ enc, const int* __restrict__ caps_in,
    const int* __restrict__ cl_in, const float* __restrict__ hs,
    const float* __restrict__ emb,
    const float* We, const float* be, const float* Wd, const float* bd,
    const float* Wsx, const float* bsx, const float* Wf, const float* bf,
    const float* Wih, const float* bih, const float* Whh, const float* bhh,
    const float* Wh0, const float* bh0, const float* Wc0, const float* bc0,
    const float* Wg, const float* bg, const float* Wo, const float* bo,
    float* __restrict__ out, int* __restrict__ wsI) {
  const int tid = threadIdx.x;
  const int blk = blockIdx.x;
  float* wsF = (float*)wsI;
  unsigned int* bar = (unsigned int*)&wsI[WSI_BAR];
  uint32* hstU = (uint32*)&wsF[F_HST];
  unsigned int barno = 0;
  __shared__ __align__(16) float sm[16896];  // 66KB union

  // ================= P0: sort + mean_enc =================
  if (blk == 0 && tid == 0) {
    int cl[BSZ]; bool used[BSZ];
    for (int i = 0; i < BSZ; i++) { cl[i] = cl_in[i]; used[i] = false; }
    for (int r = 0; r < BSZ; r++) {
      int best = -1, bv = -1;
      for (int i = 0; i < BSZ; i++)
        if (!used[i] && cl[i] > bv) { bv = cl[i]; best = i; }
      used[best] = true;
      stgi(&wsI[WSI_SORT + r], best);
      stgi(&wsI[WSI_CL + r], bv);
      stgi(&wsI[WSI_DEC + r], bv - 1);
      out[O_DEC + r] = (float)(bv - 1);
      out[O_SORT + r] = (float)best;
    }
  }
  if (blk == 1) {
    for (int d = tid; d < EDIM; d += NTHR) {
      float s = 0.f;
      for (int p = 0; p < NPIX; p++) s += enc[p * EDIM + d];
      stg(&wsF[F_MEAN + d], s * (1.f / NPIX));
    }
  }
  gbar(bar, ++barno * NBLK);

  // ================= P1: att1, att3b, h0/c0, caps (one-time) =================
  if (blk < 64) {  // att1 = enc @ We + be
    for (int pp = 0; pp < 10; pp++) {
      int p = blk * 10 + pp;
      int a = tid;
      float s = be[a];
#pragma unroll 8
      for (int k = 0; k < EDIM; k++) s = fmaf(enc[p * EDIM + k], We[k * ADIM + a], s);
      stg(&wsF[F_ATT1 + (size_t)p * ADIM + a], s);
    }
  } else if (blk < 96) {  // att3b = hs_sorted @ Ws + bs + bd
    int b = blk - 64;
    int a = tid;
    int src = wsI[WSI_SORT + b];
    float s = bsx[a] + bd[a];
#pragma unroll 8
    for (int k = 0; k < SDIM; k++) s = fmaf(hs[src * SDIM + k], Wsx[k * ADIM + a], s);
    stg(&wsF[F_ATT3B + b * ADIM + a], s);
  } else if (blk == 96) {  // h0/c0 (same across batch)
    int d = tid;
    float ha = bh0[d], ca = bc0[d];
    for (int e = 0; e < EDIM; e++) {
      float m = ldgc(&wsF[F_MEAN + e]);
      ha = fmaf(m, Wh0[e * DDIM + d], ha);
      ca = fmaf(m, Wc0[e * DDIM + d], ca);
    }
    for (int b = 0; b < BSZ; b++) {
      stg(&wsF[F_H0 + b * DDIM + d], ha);
      stg(&wsF[F_C + b * DDIM + d], ca);
    }
  } else if (blk >= 97 && blk < 129) {  // sorted caps
    int b = blk - 97;
    if (tid < SLEN) {
      int src = wsI[WSI_SORT + b];
      int cv = caps_in[src * SLEN + tid];
      stgi(&wsI[WSI_CAPS + b * SLEN + tid], cv);
      out[O_CAPS + b * SLEN + tid] = (float)cv;
    }
  }
  gbar(bar, ++barno * NBLK);

  // ================= decode loop: 3 phases/step =================
  for (int t = 0; t < TT; t++) {
    const int FH_rd = (t & 1) ? F_H1 : F_H0;
    const int FH_wr = (t & 1) ? F_H0 : F_H1;

    // ---- Phase A: [u|g|hh] = h @ [Wd|Wg|Whh]  (96 blocks x 32 cols) ----
    if (blk < 96) {
      // stage h (32x512) into LDS, pitch 516 (bank-clean), batched sc1 x8
      {
        f32x4 r0, r1, r2, r3, r4, r5, r6, r7;
        int q0 = tid * 8;
#define HSRC(qi) (&wsF[FH_rd + ((qi) >> 7) * DDIM + ((qi) & 127) * 4])
        LD4C_ISSUE(r0, HSRC(q0 + 0)); LD4C_ISSUE(r1, HSRC(q0 + 1));
        LD4C_ISSUE(r2, HSRC(q0 + 2)); LD4C_ISSUE(r3, HSRC(q0 + 3));
        LD4C_ISSUE(r4, HSRC(q0 + 4)); LD4C_ISSUE(r5, HSRC(q0 + 5));
        LD4C_ISSUE(r6, HSRC(q0 + 6)); LD4C_ISSUE(r7, HSRC(q0 + 7));
        VMWAIT();
#define HDST(qi) (*(f32x4*)&sm[((qi) >> 7) * 516 + ((qi) & 127) * 4])
        HDST(q0 + 0) = r0; HDST(q0 + 1) = r1; HDST(q0 + 2) = r2; HDST(q0 + 3) = r3;
        HDST(q0 + 4) = r4; HDST(q0 + 5) = r5; HDST(q0 + 6) = r6; HDST(q0 + 7) = r7;
#undef HSRC
#undef HDST
      }
      __syncthreads();
      const float* W; int ldw, c0, kind;
      if (blk < 16)      { W = Wd;  ldw = 512;  c0 = blk * 32;        kind = 0; }
      else if (blk < 32) { W = Wg;  ldw = 512;  c0 = (blk - 16) * 32; kind = 1; }
      else               { W = Whh; ldw = 2048; c0 = (blk - 32) * 32; kind = 2; }
      const int ks = tid >> 8;          // 0..1
      const int b  = (tid >> 3) & 31;   // 0..31
      const int cq = tid & 7;           // 0..7
      const float* wp = W + (size_t)(ks * 256) * ldw + c0 + cq * 4;
      const float* xp = &sm[b * 516 + ks * 256];
      f32x4 acc = {0.f, 0.f, 0.f, 0.f};
#pragma unroll 4
      for (int k = 0; k < 256; k++) {
        f32x4 w = *(const f32x4*)(wp + (size_t)k * ldw);
        float xv = xp[k];
        acc[0] = fmaf(xv, w[0], acc[0]); acc[1] = fmaf(xv, w[1], acc[1]);
        acc[2] = fmaf(xv, w[2], acc[2]); acc[3] = fmaf(xv, w[3], acc[3]);
      }
      __syncthreads();
      f32x4* red4 = (f32x4*)sm;
      red4[ks * 256 + (tid & 255)] = acc;
      __syncthreads();
      if (tid < 256) {
        f32x4 s4 = red4[tid];
        f32x4 s5 = red4[256 + tid];
        s4[0] += s5[0]; s4[1] += s5[1]; s4[2] += s5[2]; s4[3] += s5[3];
        const int bb = (tid >> 3) & 31, cc = tid & 7;
        const int col = c0 + cc * 4;
        if (kind == 0) {
          f32x4 a3 = *(const f32x4*)&wsF[F_ATT3B + bb * ADIM + col];
          s4[0] += a3[0]; s4[1] += a3[1]; s4[2] += a3[2]; s4[3] += a3[3];
          stg4(&wsF[F_U + bb * ADIM + col], s4);
        } else if (kind == 1) {
          f32x4 bg4 = *(const f32x4*)&bg[col];
          f32x4 g4;
          g4[0] = sigm(s4[0] + bg4[0]); g4[1] = sigm(s4[1] + bg4[1]);
          g4[2] = sigm(s4[2] + bg4[2]); g4[3] = sigm(s4[3] + bg4[3]);
          stg4(&wsF[F_G + bb * EDIM + col], g4);
        } else {
          stg4(&wsF[F_HH + bb * 2048 + col], s4);
        }
      }
    } else if (blk == 96) {  // embedding gather (float4)
      for (int j = 0; j < 4; j++) {
        int qi = tid + j * NTHR;          // 0..2047
        int b = qi >> 6, q = qi & 63;
        int tok = wsI[WSI_CAPS + b * SLEN + t];
        f32x4 e4 = *(const f32x4*)&emb[tok * EMD + q * 4];
        stg4(&wsF[F_EMBT + b * EMD + q * 4], e4);
      }
    } else if (blk == 97 || blk == 98) {  // zero awe
      int base = (blk - 97) * 2048;       // quads
      f32x4 z = {0.f, 0.f, 0.f, 0.f};
      for (int j = 0; j < 4; j++) {
        int qi = base + tid + j * NTHR;
        stg4(&wsF[F_AWE + qi * 4], z);
      }
    } else if (blk == 99) {
      if (tid < BSZ) stg(&wsF[F_DEN + tid], 0.f);
    }
    gbar(bar, ++barno * NBLK);

    // ---- Phase B: scores, exp, atomic den + atomic awe  (block = (b, ptile)) ----
    {
      const int b = blk >> 3;
      const int pt = blk & 7;
      if (tid < 128) {
        f32x4 uu; LD4C_ISSUE(uu, &wsF[F_U + b * ADIM + tid * 4]);
        f32x4 wf = *(const f32x4*)&Wf[tid * 4];
        VMWAIT();
        *(f32x4*)&sm[tid * 4] = uu;
        *(f32x4*)&sm[512 + tid * 4] = wf;
      }
      __syncthreads();
      const int wave = tid >> 6, lane = tid & 63;
      const float bf0 = bf[0];
      float dl = 0.f;
      for (int j = 0; j < 10; j++) {
        int pi = wave + j * 8;
        int p = pt * 80 + pi;
        const float* a1 = &wsF[F_ATT1 + (size_t)p * ADIM];  // plain, L2-hot
        float s = 0.f;
#pragma unroll
        for (int q = 0; q < 8; q++) {
          int a = lane + q * 64;
          float v = fmaxf(a1[a] + sm[a], 0.f);
          s = fmaf(v, sm[512 + a], s);
        }
        s += __shfl_xor(s, 1);  s += __shfl_xor(s, 2);  s += __shfl_xor(s, 4);
        s += __shfl_xor(s, 8);  s += __shfl_xor(s, 16); s += __shfl_xor(s, 32);
        float ex = expf(s + bf0);  // e is O(+-5): exact ratio without max-sub
        if (lane == 0) {
          sm[1024 + pi] = ex;
          stg(&wsF[F_WEXP + b * NPIX + p], ex);
          dl += ex;
        }
      }
      if (lane == 0) sm[1104 + wave] = dl;
      __syncthreads();
      if (tid == 0) {
        float pd = 0.f;
        for (int w = 0; w < 8; w++) pd += sm[1104 + w];
        atadd(&wsF[F_DEN + b], pd);
      }
      {  // awe partial over this p-tile
        int ec = tid;
        float acc = 0.f;
        const float* eb = &enc[(size_t)(pt * 80) * EDIM + ec];
#pragma unroll 4
        for (int i = 0; i < 80; i++) acc = fmaf(sm[1024 + i], eb[(size_t)i * EDIM], acc);
        atadd(&wsF[F_AWE + b * EDIM + ec], acc);
      }
    }
    gbar(bar, ++barno * NBLK);

    // ---- Phase D: gates = [emb|g*awe/den] @ Wih + hh; pointwise; alphas ----
    if (blk < 64) {
      const int set = blk >> 1;           // 0..31 -> 16 cols per gate
      const int bh  = blk & 1;            // b-half
      const int b0  = bh * 16;
      // stage x (16 x 768) into LDS pitch 772; batched sc1
      {
        const int row = tid >> 5;               // 0..15
        const int kb  = (tid & 31) * 24;        // 24 k per thread
        f32x4 rv[6], av[6];
        float dv = 0.f;
        if (tid < 16) { LD1C_ISSUE(dv, &wsF[F_DEN + b0 + tid]); }
#pragma unroll
        for (int q = 0; q < 6; q++) {
          int k0 = kb + q * 4;
          if (k0 < 256) {
            LD4C_ISSUE(rv[q], &wsF[F_EMBT + (b0 + row) * EMD + k0]);
          } else {
            LD4C_ISSUE(rv[q], &wsF[F_G + (b0 + row) * EDIM + (k0 - 256)]);
            LD4C_ISSUE(av[q], &wsF[F_AWE + (b0 + row) * EDIM + (k0 - 256)]);
          }
        }
        VMWAIT();
        if (tid < 16) sm[13376 + tid] = 1.f / dv;
        __syncthreads();
        float rden = sm[13376 + row];
#pragma unroll
        for (int q = 0; q < 6; q++) {
          int k0 = kb + q * 4;
          f32x4 x4 = rv[q];
          if (k0 >= 256) {
            x4[0] *= av[q][0] * rden; x4[1] *= av[q][1] * rden;
            x4[2] *= av[q][2] * rden; x4[3] *= av[q][3] * rden;
          }
          *(f32x4*)&sm[row * 772 + k0] = x4;
        }
      }
      __syncthreads();
      const int ks = tid >> 6;            // 0..7 (96 k each)
      const int bi = (tid >> 2) & 15;
      const int cq = tid & 3;
      const float* xr = &sm[bi * 772 + ks * 96];
      const float* wb = Wih + (size_t)(ks * 96) * 2048 + set * 16 + cq * 4;
      f32x4 a0 = {0,0,0,0}, a1 = {0,0,0,0}, a2 = {0,0,0,0}, a3 = {0,0,0,0};
#pragma unroll 2
      for (int k = 0; k < 96; k++) {
        const float* wr = wb + (size_t)k * 2048;
        f32x4 w0 = *(const f32x4*)(wr);
        f32x4 w1 = *(const f32x4*)(wr + 512);
        f32x4 w2 = *(const f32x4*)(wr + 1024);
        f32x4 w3 = *(const f32x4*)(wr + 1536);
        float xv = xr[k];
        a0[0]=fmaf(xv,w0[0],a0[0]); a0[1]=fmaf(xv,w0[1],a0[1]); a0[2]=fmaf(xv,w0[2],a0[2]); a0[3]=fmaf(xv,w0[3],a0[3]);
        a1[0]=fmaf(xv,w1[0],a1[0]); a1[1]=fmaf(xv,w1[1],a1[1]); a1[2]=fmaf(xv,w1[2],a1[2]); a1[3]=fmaf(xv,w1[3],a1[3]);
        a2[0]=fmaf(xv,w2[0],a2[0]); a2[1]=fmaf(xv,w2[1],a2[1]); a2[2]=fmaf(xv,w2[2],a2[2]); a2[3]=fmaf(xv,w2[3],a2[3]);
        a3[0]=fmaf(xv,w3[0],a3[0]); a3[1]=fmaf(xv,w3[1],a3[1]); a3[2]=fmaf(xv,w3[2],a3[2]); a3[3]=fmaf(xv,w3[3],a3[3]);
      }
      __syncthreads();
      f32x4* red4 = (f32x4*)sm;  // alias x-LDS (reads done)
      red4[tid * 4 + 0] = a0; red4[tid * 4 + 1] = a1;
      red4[tid * 4 + 2] = a2; red4[tid * 4 + 3] = a3;
      __syncthreads();
      if (tid < 256) {
        const int bi2 = tid >> 4, cq2 = (tid >> 2) & 3, gt = tid & 3;
        f32x4 s4 = {0,0,0,0};
#pragma unroll
        for (int k2 = 0; k2 < 8; k2++) {
          f32x4 v = red4[(k2 * 64 + bi2 * 4 + cq2) * 4 + gt];
          s4[0]+=v[0]; s4[1]+=v[1]; s4[2]+=v[2]; s4[3]+=v[3];
        }
        const int b = b0 + bi2;
        const int col = gt * 512 + set * 16 + cq2 * 4;
        f32x4 hh4 = ld4c(&wsF[F_HH + b * 2048 + col]);
        f32x4 b1 = *(const f32x4*)&bih[col];
        f32x4 b2 = *(const f32x4*)&bhh[col];
        s4[0]+=hh4[0]+b1[0]+b2[0]; s4[1]+=hh4[1]+b1[1]+b2[1];
        s4[2]+=hh4[2]+b1[2]+b2[2]; s4[3]+=hh4[3]+b1[3]+b2[3];
        *(f32x4*)&sm[12352 + bi2 * 64 + cq2 * 16 + gt * 4] = s4;
      }
      __syncthreads();
      if (tid < 128) {  // pointwise, 2 d's per thread
        const int bi2 = tid >> 3, dp = tid & 7;
        const int b = b0 + bi2;
        const bool act = t < wsI[WSI_DEC + b];
        float hw2[2], cw2[2];
#pragma unroll
        for (int e = 0; e < 2; e++) {
          int dd = dp * 2 + e;
          int base = 12352 + bi2 * 64 + (dd >> 2) * 16 + (dd & 3);
          float iv = sm[base + 0], fv = sm[base + 4], gv = sm[base + 8], ov = sm[base + 12];
          int dglob = set * 16 + dd;
          float co = wsF[F_C + b * DDIM + dglob];         // block-private plain
          float ho = ldgc(&wsF[FH_rd + b * DDIM + dglob]);
          float cn = sigm(fv) * co + sigm(iv) * tanhf(gv);
          float hn = sigm(ov) * tanhf(cn);
          float hw = act ? hn : ho;
          float cw = act ? cn : co;
          wsF[F_C + b * DDIM + dglob] = cw;
          hw2[e] = hw; cw2[e] = cw;
        }
        int dglob0 = set * 16 + dp * 2;
        f32x2 h2; h2[0] = hw2[0]; h2[1] = hw2[1];
        stg2(&wsF[FH_wr + b * DDIM + dglob0], h2);
        stgu(&hstU[((size_t)t * BSZ + b) * 256 + (dglob0 >> 1)], packbf2(hw2[0], hw2[1]));
      }
    } else if (blk < 96) {  // alphas row (b, t)
      int b = blk - 64;
      bool act = t < wsI[WSI_DEC + b];
      float rd = act ? 1.f / ldgc(&wsF[F_DEN + b]) : 0.f;
      for (int p = tid; p < NPIX; p += NTHR)
        out[O_ALPH + (size_t)(b * TT + t) * NPIX + p] =
            act ? ldgc(&wsF[F_WEXP + b * NPIX + p]) * rd : 0.f;
    }
    gbar(bar, ++barno * NBLK);
  }

  // ================= Epilogue: preds = hst(bf16) @ Wo + bo =================
  // Block = (ct, tq): fixed 256-col Wo slice (512KB) stays L2-hot across its
  // 32 timesteps; blocks on one XCD cover 4 ct's -> 2MB Wo per XCD L2.
  {
    const int xcd = blk & 7, tq = (blk >> 3) & 7, gg = blk >> 6;
    const int ct = xcd * 4 + gg;                  // 0..31
    const int cq = tid & 63, rq = tid >> 6;
    const int col4 = ct * 256 + cq * 4;
    const bool cok = col4 < VOC;
    for (int tt = tq; tt < TT; tt += 8) {
      __syncthreads();
      for (int i = tid; i < 8192; i += NTHR) {   // stage hst(tt) -> fp32 LDS
        int bb = i >> 8, kk = i & 255;
        uint32 u = hstU[((size_t)tt * BSZ + bb) * 256 + kk];  // plain: safe, see notes
        f32x2 f2;
        f2[0] = __uint_as_float(u << 16);
        f2[1] = __uint_as_float(u & 0xFFFF0000u);
        *(f32x2*)&sm[bb * 512 + kk * 2] = f2;
      }
      __syncthreads();
      if (cok) {
        const float* wop = &Wo[col4];
        f32x4 a0 = {0,0,0,0}, a1 = {0,0,0,0}, a2 = {0,0,0,0}, a3 = {0,0,0,0};
        for (int k = 0; k < 512; k += 4) {
          f32x4 w0 = *(const f32x4*)&wop[(size_t)(k + 0) * VOC];
          f32x4 w1 = *(const f32x4*)&wop[(size_t)(k + 1) * VOC];
          f32x4 w2 = *(const f32x4*)&wop[(size_t)(k + 2) * VOC];
          f32x4 w3 = *(const f32x4*)&wop[(size_t)(k + 3) * VOC];
          f32x4 h0 = *(const f32x4*)&sm[(rq * 4 + 0) * 512 + k];
          f32x4 h1 = *(const f32x4*)&sm[(rq * 4 + 1) * 512 + k];
          f32x4 h2 = *(const f32x4*)&sm[(rq * 4 + 2) * 512 + k];
          f32x4 h3 = *(const f32x4*)&sm[(rq * 4 + 3) * 512 + k];
#define ROWFMA(ACC, HV)                                                        \
  ACC[0]=fmaf(HV[0],w0[0],ACC[0]); ACC[1]=fmaf(HV[0],w0[1],ACC[1]);            \
  ACC[2]=fmaf(HV[0],w0[2],ACC[2]); ACC[3]=fmaf(HV[0],w0[3],ACC[3]);            \
  ACC[0]=fmaf(HV[1],w1[0],ACC[0]); ACC[1]=fmaf(HV[1],w1[1],ACC[1]);            \
  ACC[2]=fmaf(HV[1],w1[2],ACC[2]); ACC[3]=fmaf(HV[1],w1[3],ACC[3]);            \
  ACC[0]=fmaf(HV[2],w2[0],ACC[0]); ACC[1]=fmaf(HV[2],w2[1],ACC[1]);            \
  ACC[2]=fmaf(HV[2],w2[2],ACC[2]); ACC[3]=fmaf(HV[2],w2[3],ACC[3]);            \
  ACC[0]=fmaf(HV[3],w3[0],ACC[0]); ACC[1]=fmaf(HV[3],w3[1],ACC[1]);            \
  ACC[2]=fmaf(HV[3],w3[2],ACC[2]); ACC[3]=fmaf(HV[3],w3[3],ACC[3]);
          ROWFMA(a0, h0) ROWFMA(a1, h1) ROWFMA(a2, h2) ROWFMA(a3, h3)
#undef ROWFMA
        }
        f32x4 bo4 = *(const f32x4*)&bo[col4];
        f32x4 accs[4] = {a0, a1, a2, a3};
#pragma unroll
        for (int r = 0; r < 4; r++) {
          int b = rq * 4 + r;
          bool act = tt < wsI[WSI_DEC + b];
          f32x4 o;
          o[0] = act ? accs[r][0] + bo4[0] : 0.f;
          o[1] = act ? accs[r][1] + bo4[1] : 0.f;
          o[2] = act ? accs[r][2] + bo4[2] : 0.f;
          o[3] = act ? accs[r][3] + bo4[3] : 0.f;
          *(f32x4*)&out[O_PRED + ((size_t)b * TT + tt) * VOC + col4] = o;
        }
      }
    }
  }
}

extern "C" void kernel_launch(void* const* d_in, const int* in_sizes, int n_in,
                              void* d_out, int out_size, void* d_ws, size_t ws_size,
                              hipStream_t stream) {
  (void)in_sizes; (void)n_in; (void)out_size; (void)ws_size;
  const float* enc  = (const float*)d_in[0];
  const int* caps   = (const int*)d_in[1];
  const int* cl     = (const int*)d_in[2];
  const float* hs   = (const float*)d_in[3];
  const float* emb  = (const float*)d_in[5];
  const float* We   = (const float*)d_in[6];  const float* be  = (const float*)d_in[7];
  const float* Wd   = (const float*)d_in[8];  const float* bd  = (const float*)d_in[9];
  const float* Wsx  = (const float*)d_in[10]; const float* bsx = (const float*)d_in[11];
  const float* Wf   = (const float*)d_in[12]; const float* bf  = (const float*)d_in[13];
  const float* Wih  = (const float*)d_in[14]; const float* bih = (const float*)d_in[15];
  const float* Whh  = (const float*)d_in[16]; const float* bhh = (const float*)d_in[17];
  const float* Wh0  = (const float*)d_in[18]; const float* bh0 = (const float*)d_in[19];
  const float* Wc0  = (const float*)d_in[20]; const float* bc0 = (const float*)d_in[21];
  const float* Wg   = (const float*)d_in[22]; const float* bg  = (const float*)d_in[23];
  const float* Wo   = (const float*)d_in[24]; const float* bo  = (const float*)d_in[25];

  hipMemsetAsync(d_ws, 0, 4, stream);  // zero the barrier counter
  decoder_persistent<<<dim3(NBLK), dim3(NTHR), 0, stream>>>(
      enc, caps, cl, hs, emb, We, be, Wd, bd, Wsx, bsx, Wf, bf, Wih, bih, Whh,
      bhh, Wh0, bh0, Wc0, bc0, Wg, bg, Wo, bo, (float*)d_out, (int*)d_ws);
}